// Round 1
// baseline (3699.967 us; speedup 1.0000x reference)
//
#include <hip/hip_runtime.h>

#define P 64
#define N 2048
#define M1 512
#define M2 128
#define KNB 32

// d_out layout (floats), concatenated in reference return order
#define OFF_XG     0
#define OFF_POSG   49152
#define OFF_BATCHG 49344
#define OFF_X2     49408
#define OFF_Q2     3195136
#define OFF_BATCH2 3219712
#define OFF_VMIN   3227904
#define OFF_DIFF   3228096

// exact (uncontracted, RN) squared distance, matching jnp's ((dx^2+dy^2)+dz^2)
__device__ __forceinline__ float sqdist(float ax, float ay, float az,
                                        float bx, float by, float bz) {
#pragma clang fp contract(off)
  float dx = ax - bx, dy = ay - by, dz = az - bz;
  float r = (dx * dx + dy * dy) + dz * dz;
  return r;
}

__device__ __forceinline__ float norm_div(float v, float mn, float d) {
#pragma clang fp contract(off)
  float r = (v - mn) / d;
  return r;
}

// ---------------- misc: zero xg/pos_g, write batch_g, batch2 ----------------
__global__ void k_misc(float* __restrict__ out) {
  int i = blockIdx.x * 256 + threadIdx.x;   // grid covers 57600 exactly
  if (i < OFF_BATCHG) {
    out[i] = 0.0f;                          // xg (zero-init for atomicMax) + pos_g
  } else if (i < OFF_X2) {
    out[i] = (float)(i - OFF_BATCHG);       // batch_g = arange(P)
  } else {
    int j = i - OFF_X2;                     // j < 8192
    out[OFF_BATCH2 + j] = (float)(j >> 7);  // batch2 = repeat(arange(P), M2)
  }
}

// ---------------- normalize: v_min/diff + pn ----------------
__global__ __launch_bounds__(256) void k_norm(const float* __restrict__ pos,
                                              float* __restrict__ pn,
                                              float* __restrict__ out) {
  int p = blockIdx.x, t = threadIdx.x;
  const float* src = pos + (size_t)p * N * 3;
  float mn0 = INFINITY, mn1 = INFINITY, mn2 = INFINITY;
  float mx0 = -INFINITY, mx1 = -INFINITY, mx2 = -INFINITY;
  for (int i = t; i < N; i += 256) {
    float a = src[i*3+0], b = src[i*3+1], c = src[i*3+2];
    mn0 = fminf(mn0, a); mx0 = fmaxf(mx0, a);
    mn1 = fminf(mn1, b); mx1 = fmaxf(mx1, b);
    mn2 = fminf(mn2, c); mx2 = fmaxf(mx2, c);
  }
#pragma unroll
  for (int off = 32; off; off >>= 1) {
    mn0 = fminf(mn0, __shfl_xor(mn0, off)); mx0 = fmaxf(mx0, __shfl_xor(mx0, off));
    mn1 = fminf(mn1, __shfl_xor(mn1, off)); mx1 = fmaxf(mx1, __shfl_xor(mx1, off));
    mn2 = fminf(mn2, __shfl_xor(mn2, off)); mx2 = fmaxf(mx2, __shfl_xor(mx2, off));
  }
  __shared__ float red[4][6];
  __shared__ float sB[4];
  if ((t & 63) == 0) {
    int w = t >> 6;
    red[w][0] = mn0; red[w][1] = mn1; red[w][2] = mn2;
    red[w][3] = mx0; red[w][4] = mx1; red[w][5] = mx2;
  }
  __syncthreads();
  if (t == 0) {
    float a0 = red[0][0], a1 = red[0][1], a2 = red[0][2];
    float b0 = red[0][3], b1 = red[0][4], b2 = red[0][5];
    for (int w = 1; w < 4; ++w) {
      a0 = fminf(a0, red[w][0]); a1 = fminf(a1, red[w][1]); a2 = fminf(a2, red[w][2]);
      b0 = fmaxf(b0, red[w][3]); b1 = fmaxf(b1, red[w][4]); b2 = fmaxf(b2, red[w][5]);
    }
    float d0 = b0 - a0, d1 = b1 - a1, d2 = b2 - a2;  // plain subs, RN, no fma risk
    float diff = fmaxf(fmaxf(d0, d1), d2);
    out[OFF_VMIN + p*3 + 0] = a0;
    out[OFF_VMIN + p*3 + 1] = a1;
    out[OFF_VMIN + p*3 + 2] = a2;
    out[OFF_DIFF + p] = diff;
    sB[0] = a0; sB[1] = a1; sB[2] = a2; sB[3] = diff;
  }
  __syncthreads();
  float a0 = sB[0], a1 = sB[1], a2 = sB[2], dif = sB[3];
  for (int i = t; i < N; i += 256) {
    pn[(size_t)(p*N + i)*3 + 0] = norm_div(src[i*3+0], a0, dif);
    pn[(size_t)(p*N + i)*3 + 1] = norm_div(src[i*3+1], a1, dif);
    pn[(size_t)(p*N + i)*3 + 2] = norm_div(src[i*3+2], a2, dif);
  }
}

// ---------------- FPS: one wave per patch, exact argmax chain ----------------
template<int NP, int M, int VPT>
__global__ __launch_bounds__(64) void k_fps(const float* __restrict__ pts,
                                            int* __restrict__ idx_out) {
  int p = blockIdx.x, l = threadIdx.x;
  const float* pb = pts + (size_t)p * NP * 3;
  __shared__ float sp[NP * 3];
  for (int i = l; i < NP * 3; i += 64) sp[i] = pb[i];
  __syncthreads();
  float px[VPT], py[VPT], pz[VPT], dd[VPT];
#pragma unroll
  for (int s = 0; s < VPT; ++s) {
    int i = l + 64 * s;
    px[s] = sp[i*3]; py[s] = sp[i*3+1]; pz[s] = sp[i*3+2];
  }
  float jx = sp[0], jy = sp[1], jz = sp[2];
#pragma unroll
  for (int s = 0; s < VPT; ++s) dd[s] = sqdist(px[s], py[s], pz[s], jx, jy, jz);
  if (l == 0) idx_out[p * M] = 0;
  for (int it = 1; it < M; ++it) {
    float bv = dd[0]; int bs = 0;
#pragma unroll
    for (int s = 1; s < VPT; ++s) if (dd[s] > bv) { bv = dd[s]; bs = s; }
    int bi = l + (bs << 6);
#pragma unroll
    for (int off = 32; off; off >>= 1) {       // allreduce argmax, ties -> min idx
      float ov = __shfl_xor(bv, off); int oi = __shfl_xor(bi, off);
      if (ov > bv || (ov == bv && oi < bi)) { bv = ov; bi = oi; }
    }
    if (l == 0) idx_out[p * M + it] = bi;
    jx = sp[bi*3]; jy = sp[bi*3+1]; jz = sp[bi*3+2];
#pragma unroll
    for (int s = 0; s < VPT; ++s)
      dd[s] = fminf(dd[s], sqdist(px[s], py[s], pz[s], jx, jy, jz));
  }
}

// ---------------- gather sampled coords ----------------
__global__ void k_gather(const float* __restrict__ pts, const int* __restrict__ idx,
                         float* __restrict__ qout, int total, int M, int NP) {
  int i = blockIdx.x * 256 + threadIdx.x;
  if (i >= total) return;
  int p = i / M;
  int id = idx[i];
  const float* s = pts + ((size_t)p * NP + id) * 3;
  qout[(size_t)i*3 + 0] = s[0];
  qout[(size_t)i*3 + 1] = s[1];
  qout[(size_t)i*3 + 2] = s[2];
}

// ---------------- radius top-K: one wave per query, iterative argmin ----------------
template<int NP, int MQ, int VPT>
__global__ __launch_bounds__(256) void k_neigh(const float* __restrict__ pts,
                                               const float* __restrict__ qv,
                                               int* __restrict__ nidx,
                                               unsigned* __restrict__ vmask,
                                               float r2) {
  int t = threadIdx.x;
  int l = t & 63, w = t >> 6;
  int qi = blockIdx.x * 4 + w;
  int p = qi / MQ;                             // MQ is a power of 2 (compile-time)
  float qx = qv[(size_t)qi*3], qy = qv[(size_t)qi*3+1], qz = qv[(size_t)qi*3+2];
  const float* pb = pts + (size_t)p * NP * 3;
  float dd[VPT];
#pragma unroll
  for (int s = 0; s < VPT; ++s) {
    int i = l + 64 * s;
    dd[s] = sqdist(pb[i*3], pb[i*3+1], pb[i*3+2], qx, qy, qz);
  }
  // local argmin (ties -> smaller s == smaller global index for this layout)
  float bv = dd[0]; int bs = 0;
#pragma unroll
  for (int s = 1; s < VPT; ++s) if (dd[s] < bv) { bv = dd[s]; bs = s; }
  unsigned vb = 0;
  int base = qi * KNB;
  for (int k = 0; k < KNB; ++k) {
    float wv = bv; int wi = l + (bs << 6);
#pragma unroll
    for (int off = 32; off; off >>= 1) {       // allreduce argmin, ties -> min idx
      float ov = __shfl_xor(wv, off); int oi = __shfl_xor(wi, off);
      if (ov < wv || (ov == wv && oi < wi)) { wv = ov; wi = oi; }
    }
    if (l == 0) nidx[base + k] = wi;
    if (wv <= r2) vb |= (1u << k);
    if ((wi & 63) == l) {                      // winner lane: clear + rescan
      int os = wi >> 6;
#pragma unroll
      for (int s = 0; s < VPT; ++s) if (s == os) dd[s] = INFINITY;
      bv = dd[0]; bs = 0;
#pragma unroll
      for (int s = 1; s < VPT; ++s) if (dd[s] < bv) { bv = dd[s]; bs = s; }
    }
  }
  if (l == 0) vmask[qi] = vb;
}

// ---------------- layer1 MLP (6->64->128) + masked max, 4 queries/block ----------------
__global__ __launch_bounds__(256) void k_mlp1(
    const float* __restrict__ pn, const float* __restrict__ q1,
    const int* __restrict__ nidx, const unsigned* __restrict__ vmask,
    const float* __restrict__ W1a, const float* __restrict__ b1a,
    const float* __restrict__ W1b, const float* __restrict__ b1b,
    float* __restrict__ x1) {
  __shared__ __align__(16) float featT[6 * 132];
  __shared__ __align__(16) float h1T[64 * 132];
  __shared__ __align__(16) float wbuf[16 * 128];
  __shared__ __align__(16) float w1a_s[6 * 64];
  __shared__ float b1a_s[64], b1b_s[128];
  __shared__ int part[4 * 128];
  int t = threadIdx.x;
  int qb = blockIdx.x * 4;
  for (int i = t; i < 384; i += 256) w1a_s[i] = W1a[i];
  if (t < 64) b1a_s[t] = b1a[t];
  if (t < 128) b1b_s[t] = b1b[t];
  for (int i = t; i < 512; i += 256) part[i] = 0;
  if (t < 128) {
    int r = t, qq = r >> 5, k = r & 31;
    int qi = qb + qq, p = qi >> 9;
    int nid = nidx[qi * KNB + k];
    const float* pp = pn + ((size_t)p * N + nid) * 3;
    const float* qp = q1 + (size_t)qi * 3;
    float ax = pp[0], ay = pp[1], az = pp[2];
    featT[0*132 + r] = ax;
    featT[1*132 + r] = ay;
    featT[2*132 + r] = az;
    featT[3*132 + r] = ax - qp[0];
    featT[4*132 + r] = ay - qp[1];
    featT[5*132 + r] = az - qp[2];
  }
  __syncthreads();
  { // phase 1: rows 128 x cout 64, K=6
    int rg = t >> 4, cg = t & 15;
    float acc[8][4];
#pragma unroll
    for (int u = 0; u < 4; ++u) {
      float b = b1a_s[cg*4 + u];
#pragma unroll
      for (int v = 0; v < 8; ++v) acc[v][u] = b;
    }
#pragma unroll
    for (int j = 0; j < 6; ++j) {
      float4 w4 = *(const float4*)&w1a_s[j*64 + cg*4];
      float4 ra = *(const float4*)&featT[j*132 + rg*8];
      float4 rb = *(const float4*)&featT[j*132 + rg*8 + 4];
      float rv[8] = {ra.x, ra.y, ra.z, ra.w, rb.x, rb.y, rb.z, rb.w};
      float wv[4] = {w4.x, w4.y, w4.z, w4.w};
#pragma unroll
      for (int v = 0; v < 8; ++v)
#pragma unroll
        for (int u = 0; u < 4; ++u) acc[v][u] = fmaf(rv[v], wv[u], acc[v][u]);
    }
#pragma unroll
    for (int u = 0; u < 4; ++u)
#pragma unroll
      for (int v = 0; v < 8; ++v)
        h1T[(cg*4 + u)*132 + rg*8 + v] = fmaxf(acc[v][u], 0.0f);
  }
  __syncthreads();
  // phase 2: rows 128 x cout 128, K=64
  int rg = t >> 3, cg = t & 7;
  float acc[4][16];
#pragma unroll
  for (int u = 0; u < 16; ++u) {
    float b = b1b_s[cg*16 + u];
#pragma unroll
    for (int v = 0; v < 4; ++v) acc[v][u] = b;
  }
  for (int jc = 0; jc < 64; jc += 16) {
    __syncthreads();
    for (int i = t; i < 2048; i += 256)
      wbuf[i] = W1b[(jc + (i >> 7)) * 128 + (i & 127)];
    __syncthreads();
#pragma unroll
    for (int jj = 0; jj < 16; ++jj) {
      float4 rv4 = *(const float4*)&h1T[(jc + jj)*132 + rg*4];
      const float* wp = &wbuf[jj*128 + cg*16];
      float4 w0 = *(const float4*)&wp[0];
      float4 w1 = *(const float4*)&wp[4];
      float4 w2 = *(const float4*)&wp[8];
      float4 w3 = *(const float4*)&wp[12];
      float rv[4] = {rv4.x, rv4.y, rv4.z, rv4.w};
      float wv[16] = {w0.x,w0.y,w0.z,w0.w, w1.x,w1.y,w1.z,w1.w,
                      w2.x,w2.y,w2.z,w2.w, w3.x,w3.y,w3.z,w3.w};
#pragma unroll
      for (int v = 0; v < 4; ++v)
#pragma unroll
        for (int u = 0; u < 16; ++u) acc[v][u] = fmaf(rv[v], wv[u], acc[v][u]);
    }
  }
  int qq = rg >> 3;
  unsigned vm = vmask[qb + qq];
#pragma unroll
  for (int u = 0; u < 16; ++u) {
    float m = 0.0f;
#pragma unroll
    for (int v = 0; v < 4; ++v) {
      int k = (rg*4 + v) & 31;
      float h = fmaxf(acc[v][u], 0.0f);
      if ((vm >> k) & 1u) m = fmaxf(m, h);
    }
    atomicMax(&part[qq*128 + cg*16 + u], __float_as_int(m));
  }
  __syncthreads();
  for (int i = t; i < 512; i += 256)
    x1[(size_t)(qb + (i >> 7)) * 128 + (i & 127)] = __int_as_float(part[i]);
}

// ---------------- layer2 MLP (131->256->384) + masked max, 1 query/block ----------------
__global__ __launch_bounds__(256) void k_mlp2(
    const float* __restrict__ x1, const float* __restrict__ q1,
    const float* __restrict__ q2, const int* __restrict__ nidx,
    const unsigned* __restrict__ vmask,
    const float* __restrict__ W2a, const float* __restrict__ b2a,
    const float* __restrict__ W2b, const float* __restrict__ b2b,
    float* __restrict__ x2out) {
  __shared__ __align__(16) float featT[136 * 36];  // phase2 reuses [0,3072) as W chunk
  __shared__ __align__(16) float h1T[256 * 36];
  __shared__ __align__(16) float wb1[8 * 256];     // epilogue reuses as part[384]
  int t = threadIdx.x;
  int qi = blockIdx.x, p = qi >> 7;
  for (int i = t; i < 5 * 36; i += 256) featT[131*36 + i] = 0.0f;  // zero pad rows
  {
    int r = t & 31, cs = t >> 5;
    int nid = nidx[qi * KNB + r];
    const float* xrow = x1 + (size_t)(p * M1 + nid) * 128;
    for (int c = cs; c < 128; c += 8) featT[c*36 + r] = xrow[c];
    if (cs < 3)
      featT[(128 + cs)*36 + r] =
          q1[((size_t)p * M1 + nid)*3 + cs] - q2[(size_t)qi*3 + cs];
  }
  int rg = t >> 5, cg = t & 31;
  // phase 1: rows 32 x cout 256, K=131 (padded to 136)
  float acc1[4][8];
#pragma unroll
  for (int u = 0; u < 8; ++u) {
    float b = b2a[cg*8 + u];
#pragma unroll
    for (int v = 0; v < 4; ++v) acc1[v][u] = b;
  }
  for (int jc = 0; jc < 136; jc += 8) {
    __syncthreads();
    for (int i = t; i < 2048; i += 256) {
      int j = jc + (i >> 8);
      wb1[i] = (j < 131) ? W2a[(size_t)j*256 + (i & 255)] : 0.0f;
    }
    __syncthreads();
#pragma unroll
    for (int jj = 0; jj < 8; ++jj) {
      int j = jc + jj;
      float4 rv4 = *(const float4*)&featT[j*36 + rg*4];
      const float* wp = &wb1[jj*256 + cg*8];
      float4 w0 = *(const float4*)&wp[0];
      float4 w1 = *(const float4*)&wp[4];
      float rv[4] = {rv4.x, rv4.y, rv4.z, rv4.w};
      float wv[8] = {w0.x,w0.y,w0.z,w0.w, w1.x,w1.y,w1.z,w1.w};
#pragma unroll
      for (int v = 0; v < 4; ++v)
#pragma unroll
        for (int u = 0; u < 8; ++u) acc1[v][u] = fmaf(rv[v], wv[u], acc1[v][u]);
    }
  }
  __syncthreads();
#pragma unroll
  for (int u = 0; u < 8; ++u)
#pragma unroll
    for (int v = 0; v < 4; ++v)
      h1T[(cg*8 + u)*36 + rg*4 + v] = fmaxf(acc1[v][u], 0.0f);
  __syncthreads();
  // phase 2: rows 32 x cout 384, K=256
  float acc2[4][12];
#pragma unroll
  for (int u = 0; u < 12; ++u) {
    float b = b2b[cg*12 + u];
#pragma unroll
    for (int v = 0; v < 4; ++v) acc2[v][u] = b;
  }
  float* wb2 = featT;
  for (int jc = 0; jc < 256; jc += 8) {
    __syncthreads();
#pragma unroll
    for (int jj = 0; jj < 8; ++jj)
      for (int c = t; c < 384; c += 256)
        wb2[jj*384 + c] = W2b[(size_t)(jc + jj)*384 + c];
    __syncthreads();
#pragma unroll
    for (int jj = 0; jj < 8; ++jj) {
      float4 rv4 = *(const float4*)&h1T[(jc + jj)*36 + rg*4];
      const float* wp = &wb2[jj*384 + cg*12];
      float4 w0 = *(const float4*)&wp[0];
      float4 w1 = *(const float4*)&wp[4];
      float4 w2 = *(const float4*)&wp[8];
      float rv[4] = {rv4.x, rv4.y, rv4.z, rv4.w};
      float wv[12] = {w0.x,w0.y,w0.z,w0.w, w1.x,w1.y,w1.z,w1.w, w2.x,w2.y,w2.z,w2.w};
#pragma unroll
      for (int v = 0; v < 4; ++v)
#pragma unroll
        for (int u = 0; u < 12; ++u) acc2[v][u] = fmaf(rv[v], wv[u], acc2[v][u]);
    }
  }
  int* part = (int*)wb1;
  for (int i = t; i < 384; i += 256) part[i] = 0;
  __syncthreads();
  unsigned vm = vmask[qi];
#pragma unroll
  for (int u = 0; u < 12; ++u) {
    float m = 0.0f;
#pragma unroll
    for (int v = 0; v < 4; ++v) {
      int k = rg*4 + v;
      float h = fmaxf(acc2[v][u], 0.0f);
      if ((vm >> k) & 1u) m = fmaxf(m, h);
    }
    atomicMax(&part[cg*12 + u], __float_as_int(m));
  }
  __syncthreads();
  for (int i = t; i < 384; i += 256)
    x2out[(size_t)qi*384 + i] = __int_as_float(part[i]);
}

// ---------------- layer3 phase 1: (387->512), h1 to ws ----------------
__global__ __launch_bounds__(256) void k_mlp3_p1(
    const float* __restrict__ x2, const float* __restrict__ q2,
    const float* __restrict__ W3a, const float* __restrict__ b3a,
    float* __restrict__ h1o) {
  __shared__ __align__(16) float fb[16 * 68];
  __shared__ __align__(16) float wb[16 * 128];
  int t = threadIdx.x;
  int rc = blockIdx.x >> 2, cb = blockIdx.x & 3;
  int rowbase = rc * 64, coutbase = cb * 128;
  int rg = t >> 4, cg = t & 15;
  float acc[4][8];
#pragma unroll
  for (int u = 0; u < 8; ++u) {
    float b = b3a[coutbase + cg*8 + u];
#pragma unroll
    for (int v = 0; v < 4; ++v) acc[v][u] = b;
  }
  for (int jc = 0; jc < 400; jc += 16) {   // K=387 padded to 400
    __syncthreads();
    for (int i = t; i < 1024; i += 256) {
      int jj = i & 15, r = i >> 4;
      int j = jc + jj, row = rowbase + r;
      float v = 0.0f;
      if (j < 384) v = x2[(size_t)row*384 + j];
      else if (j < 387) v = q2[(size_t)row*3 + (j - 384)];
      fb[jj*68 + r] = v;
    }
    for (int i = t; i < 2048; i += 256) {
      int j = jc + (i >> 7);
      wb[i] = (j < 387) ? W3a[(size_t)j*512 + coutbase + (i & 127)] : 0.0f;
    }
    __syncthreads();
#pragma unroll
    for (int jj = 0; jj < 16; ++jj) {
      float4 rv4 = *(const float4*)&fb[jj*68 + rg*4];
      const float* wp = &wb[jj*128 + cg*8];
      float4 w0 = *(const float4*)&wp[0];
      float4 w1 = *(const float4*)&wp[4];
      float rv[4] = {rv4.x, rv4.y, rv4.z, rv4.w};
      float wv[8] = {w0.x,w0.y,w0.z,w0.w, w1.x,w1.y,w1.z,w1.w};
#pragma unroll
      for (int v = 0; v < 4; ++v)
#pragma unroll
        for (int u = 0; u < 8; ++u) acc[v][u] = fmaf(rv[v], wv[u], acc[v][u]);
    }
  }
#pragma unroll
  for (int v = 0; v < 4; ++v)
#pragma unroll
    for (int u = 0; u < 8; ++u)
      h1o[(size_t)(rowbase + rg*4 + v)*512 + coutbase + cg*8 + u] =
          fmaxf(acc[v][u], 0.0f);
}

// ---------------- layer3 phase 2: (512->768) + global max -> xg ----------------
__global__ __launch_bounds__(256) void k_mlp3_p2(
    const float* __restrict__ h1, const float* __restrict__ W3b,
    const float* __restrict__ b3b, float* __restrict__ xg) {
  __shared__ __align__(16) float fb[16 * 68];
  __shared__ __align__(16) float wb[16 * 192];
  __shared__ int part[192];
  int t = threadIdx.x;
  int rc = blockIdx.x >> 2, cb = blockIdx.x & 3;
  int rowbase = rc * 64, coutbase = cb * 192;
  int p = rc >> 1;
  int rg = t >> 4, cg = t & 15;
  float acc[4][12];
#pragma unroll
  for (int u = 0; u < 12; ++u) {
    float b = b3b[coutbase + cg*12 + u];
#pragma unroll
    for (int v = 0; v < 4; ++v) acc[v][u] = b;
  }
  for (int jc = 0; jc < 512; jc += 16) {
    __syncthreads();
    for (int i = t; i < 1024; i += 256) {
      int jj = i & 15, r = i >> 4;
      fb[jj*68 + r] = h1[(size_t)(rowbase + r)*512 + jc + jj];
    }
#pragma unroll
    for (int jj = 0; jj < 16; ++jj)
      for (int c = t; c < 192; c += 256)
        wb[jj*192 + c] = W3b[(size_t)(jc + jj)*768 + coutbase + c];
    __syncthreads();
#pragma unroll
    for (int jj = 0; jj < 16; ++jj) {
      float4 rv4 = *(const float4*)&fb[jj*68 + rg*4];
      const float* wp = &wb[jj*192 + cg*12];
      float4 w0 = *(const float4*)&wp[0];
      float4 w1 = *(const float4*)&wp[4];
      float4 w2 = *(const float4*)&wp[8];
      float rv[4] = {rv4.x, rv4.y, rv4.z, rv4.w};
      float wv[12] = {w0.x,w0.y,w0.z,w0.w, w1.x,w1.y,w1.z,w1.w, w2.x,w2.y,w2.z,w2.w};
#pragma unroll
      for (int v = 0; v < 4; ++v)
#pragma unroll
        for (int u = 0; u < 12; ++u) acc[v][u] = fmaf(rv[v], wv[u], acc[v][u]);
    }
  }
  for (int i = t; i < 192; i += 256) part[i] = 0;
  __syncthreads();
#pragma unroll
  for (int u = 0; u < 12; ++u) {
    float m = 0.0f;
#pragma unroll
    for (int v = 0; v < 4; ++v) m = fmaxf(m, fmaxf(acc[v][u], 0.0f));
    atomicMax(&part[cg*12 + u], __float_as_int(m));
  }
  __syncthreads();
  if (t < 192)
    atomicMax((int*)&xg[(size_t)p*768 + coutbase + t], part[t]);
}

extern "C" void kernel_launch(void* const* d_in, const int* in_sizes, int n_in,
                              void* d_out, int out_size, void* d_ws, size_t ws_size,
                              hipStream_t stream) {
  const float* pos = (const float*)d_in[0];
  // d_in[1] = pi (unused by reference)
  const float* W1a = (const float*)d_in[2];
  const float* b1a = (const float*)d_in[3];
  const float* W1b = (const float*)d_in[4];
  const float* b1b = (const float*)d_in[5];
  const float* W2a = (const float*)d_in[6];
  const float* b2a = (const float*)d_in[7];
  const float* W2b = (const float*)d_in[8];
  const float* b2b = (const float*)d_in[9];
  const float* W3a = (const float*)d_in[10];
  const float* b3a = (const float*)d_in[11];
  const float* W3b = (const float*)d_in[12];
  const float* b3b = (const float*)d_in[13];
  float* out = (float*)d_out;

  // workspace layout (~24 MB); h1_3 overlays x1 (dead after k_mlp2)
  float* pn   = (float*)d_ws;
  float* q1   = pn + (size_t)P * N * 3;
  float* x1   = q1 + (size_t)P * M1 * 3;
  float* h13  = x1;
  int* idx1   = (int*)(x1 + (size_t)P * M1 * 128);
  int* idx2   = idx1 + P * M1;
  int* nidx1  = idx2 + P * M2;
  int* nidx2  = nidx1 + (size_t)P * M1 * KNB;
  unsigned* vm1 = (unsigned*)(nidx2 + (size_t)P * M2 * KNB);
  unsigned* vm2 = vm1 + P * M1;

  k_misc<<<225, 256, 0, stream>>>(out);
  k_norm<<<P, 256, 0, stream>>>(pos, pn, out);
  k_fps<N, M1, N/64><<<P, 64, 0, stream>>>(pn, idx1);
  k_gather<<<(P*M1 + 255)/256, 256, 0, stream>>>(pn, idx1, q1, P*M1, M1, N);
  k_neigh<N, M1, N/64><<<P*M1/4, 256, 0, stream>>>(pn, q1, nidx1, vm1, 0.0225f);
  k_mlp1<<<P*M1/4, 256, 0, stream>>>(pn, q1, nidx1, vm1, W1a, b1a, W1b, b1b, x1);
  k_fps<M1, M2, M1/64><<<P, 64, 0, stream>>>(q1, idx2);
  k_gather<<<(P*M2 + 255)/256, 256, 0, stream>>>(q1, idx2, out + OFF_Q2, P*M2, M2, M1);
  k_neigh<M1, M2, M1/64><<<P*M2/4, 256, 0, stream>>>(q1, out + OFF_Q2, nidx2, vm2, 0.09f);
  k_mlp2<<<P*M2, 256, 0, stream>>>(x1, q1, out + OFF_Q2, nidx2, vm2,
                                   W2a, b2a, W2b, b2b, out + OFF_X2);
  k_mlp3_p1<<<512, 256, 0, stream>>>(out + OFF_X2, out + OFF_Q2, W3a, b3a, h13);
  k_mlp3_p2<<<512, 256, 0, stream>>>(h13, W3b, b3b, out);
}

// Round 3
// 1853.695 us; speedup vs baseline: 1.9960x; 1.9960x over previous
//
#include <hip/hip_runtime.h>

#define P 64
#define N 2048
#define M1 512
#define M2 128
#define KNB 32

// d_out layout (floats), concatenated in reference return order
#define OFF_XG     0
#define OFF_POSG   49152
#define OFF_BATCHG 49344
#define OFF_X2     49408
#define OFF_Q2     3195136
#define OFF_BATCH2 3219712
#define OFF_VMIN   3227904
#define OFF_DIFF   3228096

typedef __attribute__((ext_vector_type(8))) short s8b;
typedef __attribute__((ext_vector_type(4))) float f32x4;

__device__ __forceinline__ f32x4 mfma16(s8b a, s8b b, f32x4 c) {
  return __builtin_amdgcn_mfma_f32_16x16x32_bf16(a, b, c, 0, 0, 0);
}

// fp32 -> bf16 round-to-nearest-even
__device__ __forceinline__ unsigned short f2bf(float x) {
  unsigned u = __float_as_uint(x);
  unsigned r = (u + 0x7fffu + ((u >> 16) & 1u)) >> 16;
  return (unsigned short)r;
}

// exact (uncontracted, RN) squared distance, matching jnp's ((dx^2+dy^2)+dz^2)
__device__ __forceinline__ float sqdist(float ax, float ay, float az,
                                        float bx, float by, float bz) {
#pragma clang fp contract(off)
  float dx = ax - bx, dy = ay - by, dz = az - bz;
  float r = (dx * dx + dy * dy) + dz * dz;
  return r;
}

__device__ __forceinline__ float norm_div(float v, float mn, float d) {
#pragma clang fp contract(off)
  float r = (v - mn) / d;
  return r;
}

// ---------------- misc: zero xg/pos_g, write batch_g, batch2 ----------------
__global__ void k_misc(float* __restrict__ out) {
  int i = blockIdx.x * 256 + threadIdx.x;   // grid covers 57600 exactly
  if (i < OFF_BATCHG) {
    out[i] = 0.0f;                          // xg (zero-init for atomicMax) + pos_g
  } else if (i < OFF_X2) {
    out[i] = (float)(i - OFF_BATCHG);       // batch_g = arange(P)
  } else {
    int j = i - OFF_X2;                     // j < 8192
    out[OFF_BATCH2 + j] = (float)(j >> 7);  // batch2 = repeat(arange(P), M2)
  }
}

// ---------------- pack weights: fp32 [K][N] -> bf16 [N][Kpad] (zero pad) ----
// Wt1a [64][32] @0  | Wt1b [128][64] @2048 | Wt2a [256][160] @10240 | Wt2b [384][256] @51200
__global__ void k_pack(const float* __restrict__ W1a, const float* __restrict__ W1b,
                       const float* __restrict__ W2a, const float* __restrict__ W2b,
                       unsigned short* __restrict__ wp) {
  int i = blockIdx.x * 256 + threadIdx.x;
  if (i >= 149504) return;
  float v;
  if (i < 2048) {
    int n = i >> 5, k = i & 31;
    v = (k < 6) ? W1a[k * 64 + n] : 0.0f;
  } else if (i < 10240) {
    int j = i - 2048; int n = j >> 6, k = j & 63;
    v = W1b[k * 128 + n];
  } else if (i < 51200) {
    int j = i - 10240; int n = j / 160, k = j - n * 160;
    v = (k < 131) ? W2a[k * 256 + n] : 0.0f;
  } else {
    int j = i - 51200; int n = j >> 8, k = j & 255;
    v = W2b[k * 384 + n];
  }
  wp[i] = f2bf(v);
}

// ---------------- normalize: v_min/diff + pn ----------------
__global__ __launch_bounds__(256) void k_norm(const float* __restrict__ pos,
                                              float* __restrict__ pn,
                                              float* __restrict__ out) {
  int p = blockIdx.x, t = threadIdx.x;
  const float* src = pos + (size_t)p * N * 3;
  float mn0 = INFINITY, mn1 = INFINITY, mn2 = INFINITY;
  float mx0 = -INFINITY, mx1 = -INFINITY, mx2 = -INFINITY;
  for (int i = t; i < N; i += 256) {
    float a = src[i*3+0], b = src[i*3+1], c = src[i*3+2];
    mn0 = fminf(mn0, a); mx0 = fmaxf(mx0, a);
    mn1 = fminf(mn1, b); mx1 = fmaxf(mx1, b);
    mn2 = fminf(mn2, c); mx2 = fmaxf(mx2, c);
  }
#pragma unroll
  for (int off = 32; off; off >>= 1) {
    mn0 = fminf(mn0, __shfl_xor(mn0, off)); mx0 = fmaxf(mx0, __shfl_xor(mx0, off));
    mn1 = fminf(mn1, __shfl_xor(mn1, off)); mx1 = fmaxf(mx1, __shfl_xor(mx1, off));
    mn2 = fminf(mn2, __shfl_xor(mn2, off)); mx2 = fmaxf(mx2, __shfl_xor(mx2, off));
  }
  __shared__ float red[4][6];
  __shared__ float sB[4];
  if ((t & 63) == 0) {
    int w = t >> 6;
    red[w][0] = mn0; red[w][1] = mn1; red[w][2] = mn2;
    red[w][3] = mx0; red[w][4] = mx1; red[w][5] = mx2;
  }
  __syncthreads();
  if (t == 0) {
    float a0 = red[0][0], a1 = red[0][1], a2 = red[0][2];
    float b0 = red[0][3], b1 = red[0][4], b2 = red[0][5];
    for (int w = 1; w < 4; ++w) {
      a0 = fminf(a0, red[w][0]); a1 = fminf(a1, red[w][1]); a2 = fminf(a2, red[w][2]);
      b0 = fmaxf(b0, red[w][3]); b1 = fmaxf(b1, red[w][4]); b2 = fmaxf(b2, red[w][5]);
    }
    float d0 = b0 - a0, d1 = b1 - a1, d2 = b2 - a2;
    float diff = fmaxf(fmaxf(d0, d1), d2);
    out[OFF_VMIN + p*3 + 0] = a0;
    out[OFF_VMIN + p*3 + 1] = a1;
    out[OFF_VMIN + p*3 + 2] = a2;
    out[OFF_DIFF + p] = diff;
    sB[0] = a0; sB[1] = a1; sB[2] = a2; sB[3] = diff;
  }
  __syncthreads();
  float a0 = sB[0], a1 = sB[1], a2 = sB[2], dif = sB[3];
  for (int i = t; i < N; i += 256) {
    pn[(size_t)(p*N + i)*3 + 0] = norm_div(src[i*3+0], a0, dif);
    pn[(size_t)(p*N + i)*3 + 1] = norm_div(src[i*3+1], a1, dif);
    pn[(size_t)(p*N + i)*3 + 2] = norm_div(src[i*3+2], a2, dif);
  }
}

// ---------------- FPS: one wave per patch, exact argmax chain ----------------
template<int NP, int M, int VPT>
__global__ __launch_bounds__(64) void k_fps(const float* __restrict__ pts,
                                            int* __restrict__ idx_out) {
  int p = blockIdx.x, l = threadIdx.x;
  const float* pb = pts + (size_t)p * NP * 3;
  __shared__ float sp[NP * 3];
  for (int i = l; i < NP * 3; i += 64) sp[i] = pb[i];
  __syncthreads();
  float px[VPT], py[VPT], pz[VPT], dd[VPT];
#pragma unroll
  for (int s = 0; s < VPT; ++s) {
    int i = l + 64 * s;
    px[s] = sp[i*3]; py[s] = sp[i*3+1]; pz[s] = sp[i*3+2];
  }
  float jx = sp[0], jy = sp[1], jz = sp[2];
#pragma unroll
  for (int s = 0; s < VPT; ++s) dd[s] = sqdist(px[s], py[s], pz[s], jx, jy, jz);
  if (l == 0) idx_out[p * M] = 0;
  for (int it = 1; it < M; ++it) {
    float bv = dd[0]; int bs = 0;
#pragma unroll
    for (int s = 1; s < VPT; ++s) if (dd[s] > bv) { bv = dd[s]; bs = s; }
    int bi = l + (bs << 6);
#pragma unroll
    for (int off = 32; off; off >>= 1) {       // allreduce argmax, ties -> min idx
      float ov = __shfl_xor(bv, off); int oi = __shfl_xor(bi, off);
      if (ov > bv || (ov == bv && oi < bi)) { bv = ov; bi = oi; }
    }
    if (l == 0) idx_out[p * M + it] = bi;
    jx = sp[bi*3]; jy = sp[bi*3+1]; jz = sp[bi*3+2];
#pragma unroll
    for (int s = 0; s < VPT; ++s)
      dd[s] = fminf(dd[s], sqdist(px[s], py[s], pz[s], jx, jy, jz));
  }
}

// ---------------- gather sampled coords ----------------
__global__ void k_gather(const float* __restrict__ pts, const int* __restrict__ idx,
                         float* __restrict__ qout, int total, int M, int NP) {
  int i = blockIdx.x * 256 + threadIdx.x;
  if (i >= total) return;
  int p = i / M;
  int id = idx[i];
  const float* s = pts + ((size_t)p * NP + id) * 3;
  qout[(size_t)i*3 + 0] = s[0];
  qout[(size_t)i*3 + 1] = s[1];
  qout[(size_t)i*3 + 2] = s[2];
}

// ---------------- radius top-K: one wave per query, iterative argmin ----------------
template<int NP, int MQ, int VPT>
__global__ __launch_bounds__(256) void k_neigh(const float* __restrict__ pts,
                                               const float* __restrict__ qv,
                                               int* __restrict__ nidx,
                                               unsigned* __restrict__ vmask,
                                               float r2) {
  int t = threadIdx.x;
  int l = t & 63, w = t >> 6;
  int qi = blockIdx.x * 4 + w;
  int p = qi / MQ;
  float qx = qv[(size_t)qi*3], qy = qv[(size_t)qi*3+1], qz = qv[(size_t)qi*3+2];
  const float* pb = pts + (size_t)p * NP * 3;
  float dd[VPT];
#pragma unroll
  for (int s = 0; s < VPT; ++s) {
    int i = l + 64 * s;
    dd[s] = sqdist(pb[i*3], pb[i*3+1], pb[i*3+2], qx, qy, qz);
  }
  float bv = dd[0]; int bs = 0;
#pragma unroll
  for (int s = 1; s < VPT; ++s) if (dd[s] < bv) { bv = dd[s]; bs = s; }
  unsigned vb = 0;
  int base = qi * KNB;
  for (int k = 0; k < KNB; ++k) {
    float wv = bv; int wi = l + (bs << 6);
#pragma unroll
    for (int off = 32; off; off >>= 1) {       // allreduce argmin, ties -> min idx
      float ov = __shfl_xor(wv, off); int oi = __shfl_xor(wi, off);
      if (ov < wv || (ov == wv && oi < wi)) { wv = ov; wi = oi; }
    }
    if (l == 0) nidx[base + k] = wi;
    if (wv <= r2) vb |= (1u << k);
    if ((wi & 63) == l) {                      // winner lane: clear + rescan
      int os = wi >> 6;
#pragma unroll
      for (int s = 0; s < VPT; ++s) if (s == os) dd[s] = INFINITY;
      bv = dd[0]; bs = 0;
#pragma unroll
      for (int s = 1; s < VPT; ++s) if (dd[s] < bv) { bv = dd[s]; bs = s; }
    }
  }
  if (l == 0) vmask[qi] = vb;
}

// ---------------- layer1 MLP via MFMA: (6->64->128) + masked max ----------------
// one wave per query; 32 neighbor rows = 2 M-frags; weights from packed bf16 [n][kpad]
__global__ __launch_bounds__(256) void k1_mfma(
    const float* __restrict__ pn, const float* __restrict__ q1,
    const int* __restrict__ nidx, const unsigned* __restrict__ vmask,
    const unsigned short* __restrict__ Wa, const float* __restrict__ ba,
    const unsigned short* __restrict__ Wb, const float* __restrict__ bb,
    unsigned short* __restrict__ x1b) {
  __shared__ __align__(16) short lds[4][2304];  // per-wave: feat [32][40] / h1 [32][72]
  int t = threadIdx.x, w = t >> 6, l = t & 63;
  int qi = blockIdx.x * 4 + w;
  int p = qi >> 9;                             // M1 = 512
  int quad = l >> 4, n16 = l & 15;
  short* wl = lds[w];
  if (l < 32) {
    int nid = nidx[qi * KNB + l];
    const float* pp = pn + ((size_t)p * N + nid) * 3;
    const float* qq = q1 + (size_t)qi * 3;
    float ax = pp[0], ay = pp[1], az = pp[2];
    union { unsigned short s[8]; float4 f; } u;
    u.s[0] = f2bf(ax); u.s[1] = f2bf(ay); u.s[2] = f2bf(az);
    u.s[3] = f2bf(ax - qq[0]); u.s[4] = f2bf(ay - qq[1]); u.s[5] = f2bf(az - qq[2]);
    u.s[6] = 0; u.s[7] = 0;
    float4 z = {0.f, 0.f, 0.f, 0.f};
    float4* d = (float4*)(wl + l * 40);
    d[0] = u.f; d[1] = z; d[2] = z; d[3] = z;
  }
  __syncthreads();
  s8b A1[2];
#pragma unroll
  for (int mf = 0; mf < 2; ++mf)
    A1[mf] = *(const s8b*)(wl + (mf*16 + n16)*40 + quad*8);
  f32x4 zero4 = {0.f, 0.f, 0.f, 0.f};
  {
    f32x4 acc[2][4];
#pragma unroll
    for (int mf = 0; mf < 2; ++mf)
#pragma unroll
      for (int nf = 0; nf < 4; ++nf) acc[mf][nf] = zero4;
    s8b B[4];
#pragma unroll
    for (int nf = 0; nf < 4; ++nf)
      B[nf] = *(const s8b*)(Wa + (nf*16 + n16)*32 + quad*8);
#pragma unroll
    for (int mf = 0; mf < 2; ++mf)
#pragma unroll
      for (int nf = 0; nf < 4; ++nf)
        acc[mf][nf] = mfma16(A1[mf], B[nf], acc[mf][nf]);
#pragma unroll
    for (int nf = 0; nf < 4; ++nf) {
      int col = nf*16 + n16;
      float bias = ba[col];
#pragma unroll
      for (int mf = 0; mf < 2; ++mf)
#pragma unroll
        for (int r = 0; r < 4; ++r) {
          int row = mf*16 + quad*4 + r;
          float h = fmaxf(acc[mf][nf][r] + bias, 0.0f);
          *(unsigned short*)(wl + row*72 + col) = f2bf(h);
        }
    }
  }
  __syncthreads();
  s8b A2[2][2];
#pragma unroll
  for (int mf = 0; mf < 2; ++mf)
#pragma unroll
    for (int kf = 0; kf < 2; ++kf)
      A2[mf][kf] = *(const s8b*)(wl + (mf*16 + n16)*72 + kf*32 + quad*8);
  unsigned vm = vmask[qi];
#pragma unroll
  for (int nc = 0; nc < 2; ++nc) {
    f32x4 acc[2][4];
#pragma unroll
    for (int mf = 0; mf < 2; ++mf)
#pragma unroll
      for (int nf = 0; nf < 4; ++nf) acc[mf][nf] = zero4;
#pragma unroll
    for (int kf = 0; kf < 2; ++kf) {
      s8b B[4];
#pragma unroll
      for (int nf = 0; nf < 4; ++nf)
        B[nf] = *(const s8b*)(Wb + (nc*64 + nf*16 + n16)*64 + kf*32 + quad*8);
#pragma unroll
      for (int mf = 0; mf < 2; ++mf)
#pragma unroll
        for (int nf = 0; nf < 4; ++nf)
          acc[mf][nf] = mfma16(A2[mf][kf], B[nf], acc[mf][nf]);
    }
#pragma unroll
    for (int nf = 0; nf < 4; ++nf) {
      int col = nc*64 + nf*16 + n16;
      float bias = bb[col];
      float m = 0.0f;
#pragma unroll
      for (int mf = 0; mf < 2; ++mf)
#pragma unroll
        for (int r = 0; r < 4; ++r) {
          int row = mf*16 + quad*4 + r;
          float h = fmaxf(acc[mf][nf][r] + bias, 0.0f);
          if ((vm >> row) & 1u) m = fmaxf(m, h);
        }
      m = fmaxf(m, __shfl_xor(m, 16));
      m = fmaxf(m, __shfl_xor(m, 32));
      if (quad == 0) x1b[(size_t)qi * 128 + col] = f2bf(m);
    }
  }
}

// ---------------- layer2 MLP via MFMA: (131->256->384) + masked max ----------------
__global__ __launch_bounds__(256) void k2_mfma(
    const unsigned short* __restrict__ x1b, const float* __restrict__ q1,
    const float* __restrict__ q2, const int* __restrict__ nidx,
    const unsigned* __restrict__ vmask,
    const unsigned short* __restrict__ Wa, const float* __restrict__ ba,
    const unsigned short* __restrict__ Wb, const float* __restrict__ bb,
    float* __restrict__ x2out) {
  __shared__ __align__(16) short lds[4][8448];  // per-wave: feat [32][168] / h1 [32][264]
  int t = threadIdx.x, w = t >> 6, l = t & 63;
  int qi = blockIdx.x * 4 + w;
  int p = qi >> 7;                             // M2 = 128
  int quad = l >> 4, n16 = l & 15;
  short* wl = lds[w];
  {                                            // gather x1 rows (bf16): 2 lanes/row,
    int r = l >> 1, h = l & 1;                 // half-row = 64 bf16 = 8 x float4
    int nid = nidx[qi * KNB + r];
    const float4* s4 = (const float4*)(x1b + (((size_t)p * M1 + nid) << 7) + h * 64);
    float4* d4 = (float4*)(wl + r * 168 + h * 64);
#pragma unroll
    for (int c = 0; c < 8; ++c) d4[c] = s4[c];
  }
  if (l < 32) {                                // rel coords + zero pad k=128..167
    int nid = nidx[qi * KNB + l];
    const float* qn = q1 + ((size_t)p * M1 + nid) * 3;
    const float* qq = q2 + (size_t)qi * 3;
    union { unsigned short s[8]; float4 f; } u;
    u.s[0] = f2bf(qn[0] - qq[0]);
    u.s[1] = f2bf(qn[1] - qq[1]);
    u.s[2] = f2bf(qn[2] - qq[2]);
    u.s[3] = 0; u.s[4] = 0; u.s[5] = 0; u.s[6] = 0; u.s[7] = 0;
    float4 z = {0.f, 0.f, 0.f, 0.f};
    float4* d = (float4*)(wl + l * 168 + 128);
    d[0] = u.f; d[1] = z; d[2] = z; d[3] = z; d[4] = z;
  }
  __syncthreads();
  s8b A1[2][5];
#pragma unroll
  for (int mf = 0; mf < 2; ++mf)
#pragma unroll
    for (int kf = 0; kf < 5; ++kf)
      A1[mf][kf] = *(const s8b*)(wl + (mf*16 + n16)*168 + kf*32 + quad*8);
  f32x4 zero4 = {0.f, 0.f, 0.f, 0.f};
  // GEMM1 -> h1 (ReLU, bf16) back into same per-wave LDS region, stride 264
#pragma unroll
  for (int nc = 0; nc < 4; ++nc) {
    f32x4 acc[2][4];
#pragma unroll
    for (int mf = 0; mf < 2; ++mf)
#pragma unroll
      for (int nf = 0; nf < 4; ++nf) acc[mf][nf] = zero4;
#pragma unroll
    for (int kf = 0; kf < 5; ++kf) {
      s8b B[4];
#pragma unroll
      for (int nf = 0; nf < 4; ++nf)
        B[nf] = *(const s8b*)(Wa + (nc*64 + nf*16 + n16)*160 + kf*32 + quad*8);
#pragma unroll
      for (int mf = 0; mf < 2; ++mf)
#pragma unroll
        for (int nf = 0; nf < 4; ++nf)
          acc[mf][nf] = mfma16(A1[mf][kf], B[nf], acc[mf][nf]);
    }
#pragma unroll
    for (int nf = 0; nf < 4; ++nf) {
      int col = nc*64 + nf*16 + n16;
      float bias = ba[col];
#pragma unroll
      for (int mf = 0; mf < 2; ++mf)
#pragma unroll
        for (int r = 0; r < 4; ++r) {
          int row = mf*16 + quad*4 + r;
          float h = fmaxf(acc[mf][nf][r] + bias, 0.0f);
          *(unsigned short*)(wl + row*264 + col) = f2bf(h);
        }
    }
  }
  __syncthreads();
  s8b A2[2][8];
#pragma unroll
  for (int mf = 0; mf < 2; ++mf)
#pragma unroll
    for (int kf = 0; kf < 8; ++kf)
      A2[mf][kf] = *(const s8b*)(wl + (mf*16 + n16)*264 + kf*32 + quad*8);
  unsigned vm = vmask[qi];
#pragma unroll
  for (int nc = 0; nc < 6; ++nc) {
    f32x4 acc[2][4];
#pragma unroll
    for (int mf = 0; mf < 2; ++mf)
#pragma unroll
      for (int nf = 0; nf < 4; ++nf) acc[mf][nf] = zero4;
#pragma unroll
    for (int kf = 0; kf < 8; ++kf) {
      s8b B[4];
#pragma unroll
      for (int nf = 0; nf < 4; ++nf)
        B[nf] = *(const s8b*)(Wb + (nc*64 + nf*16 + n16)*256 + kf*32 + quad*8);
#pragma unroll
      for (int mf = 0; mf < 2; ++mf)
#pragma unroll
        for (int nf = 0; nf < 4; ++nf)
          acc[mf][nf] = mfma16(A2[mf][kf], B[nf], acc[mf][nf]);
    }
#pragma unroll
    for (int nf = 0; nf < 4; ++nf) {
      int col = nc*64 + nf*16 + n16;
      float bias = bb[col];
      float m = 0.0f;
#pragma unroll
      for (int mf = 0; mf < 2; ++mf)
#pragma unroll
        for (int r = 0; r < 4; ++r) {
          int row = mf*16 + quad*4 + r;
          float h = fmaxf(acc[mf][nf][r] + bias, 0.0f);
          if ((vm >> row) & 1u) m = fmaxf(m, h);
        }
      m = fmaxf(m, __shfl_xor(m, 16));
      m = fmaxf(m, __shfl_xor(m, 32));
      if (quad == 0) x2out[(size_t)qi * 384 + col] = m;
    }
  }
}

// ---------------- layer3 phase 1: (387->512), h1 to ws (fp32) ----------------
__global__ __launch_bounds__(256) void k_mlp3_p1(
    const float* __restrict__ x2, const float* __restrict__ q2,
    const float* __restrict__ W3a, const float* __restrict__ b3a,
    float* __restrict__ h1o) {
  __shared__ __align__(16) float fb[16 * 68];
  __shared__ __align__(16) float wb[16 * 128];
  int t = threadIdx.x;
  int rc = blockIdx.x >> 2, cb = blockIdx.x & 3;
  int rowbase = rc * 64, coutbase = cb * 128;
  int rg = t >> 4, cg = t & 15;
  float acc[4][8];
#pragma unroll
  for (int u = 0; u < 8; ++u) {
    float b = b3a[coutbase + cg*8 + u];
#pragma unroll
    for (int v = 0; v < 4; ++v) acc[v][u] = b;
  }
  for (int jc = 0; jc < 400; jc += 16) {
    __syncthreads();
    for (int i = t; i < 1024; i += 256) {
      int jj = i & 15, r = i >> 4;
      int j = jc + jj, row = rowbase + r;
      float v = 0.0f;
      if (j < 384) v = x2[(size_t)row*384 + j];
      else if (j < 387) v = q2[(size_t)row*3 + (j - 384)];
      fb[jj*68 + r] = v;
    }
    for (int i = t; i < 2048; i += 256) {
      int j = jc + (i >> 7);
      wb[i] = (j < 387) ? W3a[(size_t)j*512 + coutbase + (i & 127)] : 0.0f;
    }
    __syncthreads();
#pragma unroll
    for (int jj = 0; jj < 16; ++jj) {
      float4 rv4 = *(const float4*)&fb[jj*68 + rg*4];
      const float* wp = &wb[jj*128 + cg*8];
      float4 w0 = *(const float4*)&wp[0];
      float4 w1 = *(const float4*)&wp[4];
      float rv[4] = {rv4.x, rv4.y, rv4.z, rv4.w};
      float wv[8] = {w0.x,w0.y,w0.z,w0.w, w1.x,w1.y,w1.z,w1.w};
#pragma unroll
      for (int v = 0; v < 4; ++v)
#pragma unroll
        for (int u = 0; u < 8; ++u) acc[v][u] = fmaf(rv[v], wv[u], acc[v][u]);
    }
  }
#pragma unroll
  for (int v = 0; v < 4; ++v)
#pragma unroll
    for (int u = 0; u < 8; ++u)
      h1o[(size_t)(rowbase + rg*4 + v)*512 + coutbase + cg*8 + u] =
          fmaxf(acc[v][u], 0.0f);
}

// ---------------- layer3 phase 2: (512->768) + global max -> xg ----------------
__global__ __launch_bounds__(256) void k_mlp3_p2(
    const float* __restrict__ h1, const float* __restrict__ W3b,
    const float* __restrict__ b3b, float* __restrict__ xg) {
  __shared__ __align__(16) float fb[16 * 68];
  __shared__ __align__(16) float wb[16 * 192];
  __shared__ int part[192];
  int t = threadIdx.x;
  int rc = blockIdx.x >> 2, cb = blockIdx.x & 3;
  int rowbase = rc * 64, coutbase = cb * 192;
  int p = rc >> 1;
  int rg = t >> 4, cg = t & 15;
  float acc[4][12];
#pragma unroll
  for (int u = 0; u < 12; ++u) {
    float b = b3b[coutbase + cg*12 + u];
#pragma unroll
    for (int v = 0; v < 4; ++v) acc[v][u] = b;
  }
  for (int jc = 0; jc < 512; jc += 16) {
    __syncthreads();
    for (int i = t; i < 1024; i += 256) {
      int jj = i & 15, r = i >> 4;
      fb[jj*68 + r] = h1[(size_t)(rowbase + r)*512 + jc + jj];
    }
#pragma unroll
    for (int jj = 0; jj < 16; ++jj)
      for (int c = t; c < 192; c += 256)
        wb[jj*192 + c] = W3b[(size_t)(jc + jj)*768 + coutbase + c];
    __syncthreads();
#pragma unroll
    for (int jj = 0; jj < 16; ++jj) {
      float4 rv4 = *(const float4*)&fb[jj*68 + rg*4];
      const float* wp = &wb[jj*192 + cg*12];
      float4 w0 = *(const float4*)&wp[0];
      float4 w1 = *(const float4*)&wp[4];
      float4 w2 = *(const float4*)&wp[8];
      float rv[4] = {rv4.x, rv4.y, rv4.z, rv4.w};
      float wv[12] = {w0.x,w0.y,w0.z,w0.w, w1.x,w1.y,w1.z,w1.w, w2.x,w2.y,w2.z,w2.w};
#pragma unroll
      for (int v = 0; v < 4; ++v)
#pragma unroll
        for (int u = 0; u < 12; ++u) acc[v][u] = fmaf(rv[v], wv[u], acc[v][u]);
    }
  }
  for (int i = t; i < 192; i += 256) part[i] = 0;
  __syncthreads();
#pragma unroll
  for (int u = 0; u < 12; ++u) {
    float m = 0.0f;
#pragma unroll
    for (int v = 0; v < 4; ++v) m = fmaxf(m, fmaxf(acc[v][u], 0.0f));
    atomicMax(&part[cg*12 + u], __float_as_int(m));
  }
  __syncthreads();
  if (t < 192)
    atomicMax((int*)&xg[(size_t)p*768 + coutbase + t], part[t]);
}

extern "C" void kernel_launch(void* const* d_in, const int* in_sizes, int n_in,
                              void* d_out, int out_size, void* d_ws, size_t ws_size,
                              hipStream_t stream) {
  const float* pos = (const float*)d_in[0];
  const float* W1a = (const float*)d_in[2];
  const float* b1a = (const float*)d_in[3];
  const float* W1b = (const float*)d_in[4];
  const float* b1b = (const float*)d_in[5];
  const float* W2a = (const float*)d_in[6];
  const float* b2a = (const float*)d_in[7];
  const float* W2b = (const float*)d_in[8];
  const float* b2b = (const float*)d_in[9];
  const float* W3a = (const float*)d_in[10];
  const float* b3a = (const float*)d_in[11];
  const float* W3b = (const float*)d_in[12];
  const float* b3b = (const float*)d_in[13];
  float* out = (float*)d_out;

  // workspace layout (~24.6 MB)
  float* pn   = (float*)d_ws;                       // 393216 f
  float* q1   = pn + (size_t)P * N * 3;             // 98304 f
  float* big  = q1 + (size_t)P * M1 * 3;            // 4194304 f: x1b(bf16) then h13(fp32)
  unsigned short* x1b = (unsigned short*)big;       // 32768*128 shorts
  float* h13  = big;                                // 8192*512 floats (x1b dead by then)
  unsigned short* wp  = (unsigned short*)(big + 4194304);  // 149504 shorts
  unsigned short* Wt1a = wp;
  unsigned short* Wt1b = wp + 2048;
  unsigned short* Wt2a = wp + 10240;
  unsigned short* Wt2b = wp + 51200;
  int* idx1   = (int*)(big + 4194304 + 74752);
  int* idx2   = idx1 + P * M1;
  int* nidx1  = idx2 + P * M2;
  int* nidx2  = nidx1 + (size_t)P * M1 * KNB;
  unsigned* vm1 = (unsigned*)(nidx2 + (size_t)P * M2 * KNB);
  unsigned* vm2 = vm1 + P * M1;

  k_misc<<<225, 256, 0, stream>>>(out);
  k_pack<<<584, 256, 0, stream>>>(W1a, W1b, W2a, W2b, wp);
  k_norm<<<P, 256, 0, stream>>>(pos, pn, out);
  k_fps<N, M1, N/64><<<P, 64, 0, stream>>>(pn, idx1);
  k_gather<<<(P*M1 + 255)/256, 256, 0, stream>>>(pn, idx1, q1, P*M1, M1, N);
  k_neigh<N, M1, N/64><<<P*M1/4, 256, 0, stream>>>(pn, q1, nidx1, vm1, 0.0225f);
  k1_mfma<<<P*M1/4, 256, 0, stream>>>(pn, q1, nidx1, vm1, Wt1a, b1a, Wt1b, b1b, x1b);
  k_fps<M1, M2, M1/64><<<P, 64, 0, stream>>>(q1, idx2);
  k_gather<<<(P*M2 + 255)/256, 256, 0, stream>>>(q1, idx2, out + OFF_Q2, P*M2, M2, M1);
  k_neigh<M1, M2, M1/64><<<P*M2/4, 256, 0, stream>>>(q1, out + OFF_Q2, nidx2, vm2, 0.09f);
  k2_mfma<<<P*M2/4, 256, 0, stream>>>(x1b, q1, out + OFF_Q2, nidx2, vm2,
                                      Wt2a, b2a, Wt2b, b2b, out + OFF_X2);
  k_mlp3_p1<<<512, 256, 0, stream>>>(out + OFF_X2, out + OFF_Q2, W3a, b3a, h13);
  k_mlp3_p2<<<512, 256, 0, stream>>>(h13, W3b, b3b, out);
}

// Round 4
// 1768.204 us; speedup vs baseline: 2.0925x; 1.0483x over previous
//
#include <hip/hip_runtime.h>

#define P 64
#define N 2048
#define M1 512
#define M2 128
#define KNB 32

// d_out layout (floats), concatenated in reference return order
#define OFF_XG     0
#define OFF_POSG   49152
#define OFF_BATCHG 49344
#define OFF_X2     49408
#define OFF_Q2     3195136
#define OFF_BATCH2 3219712
#define OFF_VMIN   3227904
#define OFF_DIFF   3228096

typedef __attribute__((ext_vector_type(8))) short s8b;
typedef __attribute__((ext_vector_type(4))) float f32x4;

__device__ __forceinline__ f32x4 mfma16(s8b a, s8b b, f32x4 c) {
  return __builtin_amdgcn_mfma_f32_16x16x32_bf16(a, b, c, 0, 0, 0);
}

// fp32 -> bf16 round-to-nearest-even
__device__ __forceinline__ unsigned short f2bf(float x) {
  unsigned u = __float_as_uint(x);
  unsigned r = (u + 0x7fffu + ((u >> 16) & 1u)) >> 16;
  return (unsigned short)r;
}

// exact (uncontracted, RN) squared distance, matching jnp's ((dx^2+dy^2)+dz^2)
__device__ __forceinline__ float sqdist(float ax, float ay, float az,
                                        float bx, float by, float bz) {
#pragma clang fp contract(off)
  float dx = ax - bx, dy = ay - by, dz = az - bz;
  float r = (dx * dx + dy * dy) + dz * dz;
  return r;
}

__device__ __forceinline__ float norm_div(float v, float mn, float d) {
#pragma clang fp contract(off)
  float r = (v - mn) / d;
  return r;
}

// ---------------- misc: zero xg/pos_g, write batch_g, batch2 ----------------
__global__ void k_misc(float* __restrict__ out) {
  int i = blockIdx.x * 256 + threadIdx.x;   // grid covers 57600 exactly
  if (i < OFF_BATCHG) {
    out[i] = 0.0f;                          // xg (zero-init for atomicMax) + pos_g
  } else if (i < OFF_X2) {
    out[i] = (float)(i - OFF_BATCHG);       // batch_g = arange(P)
  } else {
    int j = i - OFF_X2;                     // j < 8192
    out[OFF_BATCH2 + j] = (float)(j >> 7);  // batch2 = repeat(arange(P), M2)
  }
}

// ---------------- pack weights: fp32 [K][N] -> bf16 [N][Kpad] (zero pad) ----
// Wt1a [64][32] @0  | Wt1b [128][64] @2048 | Wt2a [256][160] @10240 | Wt2b [384][256] @51200
__global__ void k_pack(const float* __restrict__ W1a, const float* __restrict__ W1b,
                       const float* __restrict__ W2a, const float* __restrict__ W2b,
                       unsigned short* __restrict__ wp) {
  int i = blockIdx.x * 256 + threadIdx.x;
  if (i >= 149504) return;
  float v;
  if (i < 2048) {
    int n = i >> 5, k = i & 31;
    v = (k < 6) ? W1a[k * 64 + n] : 0.0f;
  } else if (i < 10240) {
    int j = i - 2048; int n = j >> 6, k = j & 63;
    v = W1b[k * 128 + n];
  } else if (i < 51200) {
    int j = i - 10240; int n = j / 160, k = j - n * 160;
    v = (k < 131) ? W2a[k * 256 + n] : 0.0f;
  } else {
    int j = i - 51200; int n = j >> 8, k = j & 255;
    v = W2b[k * 384 + n];
  }
  wp[i] = f2bf(v);
}

// ---------------- normalize: v_min/diff + pn ----------------
__global__ __launch_bounds__(256) void k_norm(const float* __restrict__ pos,
                                              float* __restrict__ pn,
                                              float* __restrict__ out) {
  int p = blockIdx.x, t = threadIdx.x;
  const float* src = pos + (size_t)p * N * 3;
  float mn0 = INFINITY, mn1 = INFINITY, mn2 = INFINITY;
  float mx0 = -INFINITY, mx1 = -INFINITY, mx2 = -INFINITY;
  for (int i = t; i < N; i += 256) {
    float a = src[i*3+0], b = src[i*3+1], c = src[i*3+2];
    mn0 = fminf(mn0, a); mx0 = fmaxf(mx0, a);
    mn1 = fminf(mn1, b); mx1 = fmaxf(mx1, b);
    mn2 = fminf(mn2, c); mx2 = fmaxf(mx2, c);
  }
#pragma unroll
  for (int off = 32; off; off >>= 1) {
    mn0 = fminf(mn0, __shfl_xor(mn0, off)); mx0 = fmaxf(mx0, __shfl_xor(mx0, off));
    mn1 = fminf(mn1, __shfl_xor(mn1, off)); mx1 = fmaxf(mx1, __shfl_xor(mx1, off));
    mn2 = fminf(mn2, __shfl_xor(mn2, off)); mx2 = fmaxf(mx2, __shfl_xor(mx2, off));
  }
  __shared__ float red[4][6];
  __shared__ float sB[4];
  if ((t & 63) == 0) {
    int w = t >> 6;
    red[w][0] = mn0; red[w][1] = mn1; red[w][2] = mn2;
    red[w][3] = mx0; red[w][4] = mx1; red[w][5] = mx2;
  }
  __syncthreads();
  if (t == 0) {
    float a0 = red[0][0], a1 = red[0][1], a2 = red[0][2];
    float b0 = red[0][3], b1 = red[0][4], b2 = red[0][5];
    for (int w = 1; w < 4; ++w) {
      a0 = fminf(a0, red[w][0]); a1 = fminf(a1, red[w][1]); a2 = fminf(a2, red[w][2]);
      b0 = fmaxf(b0, red[w][3]); b1 = fmaxf(b1, red[w][4]); b2 = fmaxf(b2, red[w][5]);
    }
    float d0 = b0 - a0, d1 = b1 - a1, d2 = b2 - a2;
    float diff = fmaxf(fmaxf(d0, d1), d2);
    out[OFF_VMIN + p*3 + 0] = a0;
    out[OFF_VMIN + p*3 + 1] = a1;
    out[OFF_VMIN + p*3 + 2] = a2;
    out[OFF_DIFF + p] = diff;
    sB[0] = a0; sB[1] = a1; sB[2] = a2; sB[3] = diff;
  }
  __syncthreads();
  float a0 = sB[0], a1 = sB[1], a2 = sB[2], dif = sB[3];
  for (int i = t; i < N; i += 256) {
    pn[(size_t)(p*N + i)*3 + 0] = norm_div(src[i*3+0], a0, dif);
    pn[(size_t)(p*N + i)*3 + 1] = norm_div(src[i*3+1], a1, dif);
    pn[(size_t)(p*N + i)*3 + 2] = norm_div(src[i*3+2], a2, dif);
  }
}

// ---------------- FPS: one 256-thread block per patch, exact argmax chain ----
// 4 waves; per-iter: local argmax -> wave shuffle allreduce -> LDS cross-wave
// combine (parity double-buffer, single barrier per iteration).
template<int NP, int M>
__global__ __launch_bounds__(256) void k_fps2(const float* __restrict__ pts,
                                              int* __restrict__ idx_out) {
  constexpr int VPT = NP / 256;
  int p = blockIdx.x, t = threadIdx.x;
  int l = t & 63, w = t >> 6;
  __shared__ float sp[NP * 3];
  __shared__ float redv[2][4];
  __shared__ int redi[2][4];
  const float* pb = pts + (size_t)p * NP * 3;
  for (int i = t; i < NP * 3; i += 256) sp[i] = pb[i];
  __syncthreads();
  float px[VPT], py[VPT], pz[VPT], dd[VPT];
  float jx = sp[0], jy = sp[1], jz = sp[2];
#pragma unroll
  for (int s = 0; s < VPT; ++s) {
    int i = t * VPT + s;
    px[s] = sp[i*3]; py[s] = sp[i*3+1]; pz[s] = sp[i*3+2];
    dd[s] = sqdist(px[s], py[s], pz[s], jx, jy, jz);
  }
  if (t == 0) idx_out[p * M] = 0;
  for (int it = 1; it < M; ++it) {
    float bv = dd[0]; int bs = 0;
#pragma unroll
    for (int s = 1; s < VPT; ++s) if (dd[s] > bv) { bv = dd[s]; bs = s; }
    int bi = t * VPT + bs;
#pragma unroll
    for (int off = 32; off; off >>= 1) {       // wave allreduce argmax, ties -> min idx
      float ov = __shfl_xor(bv, off); int oi = __shfl_xor(bi, off);
      if (ov > bv || (ov == bv && oi < bi)) { bv = ov; bi = oi; }
    }
    int par = it & 1;
    if (l == 0) { redv[par][w] = bv; redi[par][w] = bi; }
    __syncthreads();
    float fv = redv[par][0]; int fi = redi[par][0];
#pragma unroll
    for (int w2 = 1; w2 < 4; ++w2) {
      float ov = redv[par][w2]; int oi = redi[par][w2];
      if (ov > fv || (ov == fv && oi < fi)) { fv = ov; fi = oi; }
    }
    if (t == 0) idx_out[p * M + it] = fi;
    jx = sp[fi*3]; jy = sp[fi*3+1]; jz = sp[fi*3+2];
#pragma unroll
    for (int s = 0; s < VPT; ++s)
      dd[s] = fminf(dd[s], sqdist(px[s], py[s], pz[s], jx, jy, jz));
  }
}

// ---------------- gather sampled coords ----------------
__global__ void k_gather(const float* __restrict__ pts, const int* __restrict__ idx,
                         float* __restrict__ qout, int total, int M, int NP) {
  int i = blockIdx.x * 256 + threadIdx.x;
  if (i >= total) return;
  int p = i / M;
  int id = idx[i];
  const float* s = pts + ((size_t)p * NP + id) * 3;
  qout[(size_t)i*3 + 0] = s[0];
  qout[(size_t)i*3 + 1] = s[1];
  qout[(size_t)i*3 + 2] = s[2];
}

// ---------------- radius top-K: one wave per query, iterative argmin ----------------
template<int NP, int MQ, int VPT>
__global__ __launch_bounds__(256) void k_neigh(const float* __restrict__ pts,
                                               const float* __restrict__ qv,
                                               int* __restrict__ nidx,
                                               unsigned* __restrict__ vmask,
                                               float r2) {
  int t = threadIdx.x;
  int l = t & 63, w = t >> 6;
  int qi = blockIdx.x * 4 + w;
  int p = qi / MQ;
  float qx = qv[(size_t)qi*3], qy = qv[(size_t)qi*3+1], qz = qv[(size_t)qi*3+2];
  const float* pb = pts + (size_t)p * NP * 3;
  float dd[VPT];
#pragma unroll
  for (int s = 0; s < VPT; ++s) {
    int i = l + 64 * s;
    dd[s] = sqdist(pb[i*3], pb[i*3+1], pb[i*3+2], qx, qy, qz);
  }
  float bv = dd[0]; int bs = 0;
#pragma unroll
  for (int s = 1; s < VPT; ++s) if (dd[s] < bv) { bv = dd[s]; bs = s; }
  unsigned vb = 0;
  int base = qi * KNB;
  for (int k = 0; k < KNB; ++k) {
    float wv = bv; int wi = l + (bs << 6);
#pragma unroll
    for (int off = 32; off; off >>= 1) {       // allreduce argmin, ties -> min idx
      float ov = __shfl_xor(wv, off); int oi = __shfl_xor(wi, off);
      if (ov < wv || (ov == wv && oi < wi)) { wv = ov; wi = oi; }
    }
    if (l == 0) nidx[base + k] = wi;
    if (wv <= r2) vb |= (1u << k);
    if ((wi & 63) == l) {                      // winner lane: clear + rescan
      int os = wi >> 6;
#pragma unroll
      for (int s = 0; s < VPT; ++s) if (s == os) dd[s] = INFINITY;
      bv = dd[0]; bs = 0;
#pragma unroll
      for (int s = 1; s < VPT; ++s) if (dd[s] < bv) { bv = dd[s]; bs = s; }
    }
  }
  if (l == 0) vmask[qi] = vb;
}

// ---------------- layer1 MLP via MFMA: (6->64->128) + masked max ----------------
// one wave per query; 32 neighbor rows = 2 M-frags; weights from packed bf16 [n][kpad]
__global__ __launch_bounds__(256) void k1_mfma(
    const float* __restrict__ pn, const float* __restrict__ q1,
    const int* __restrict__ nidx, const unsigned* __restrict__ vmask,
    const unsigned short* __restrict__ Wa, const float* __restrict__ ba,
    const unsigned short* __restrict__ Wb, const float* __restrict__ bb,
    unsigned short* __restrict__ x1b) {
  __shared__ __align__(16) short lds[4][2304];  // per-wave: feat [32][40] / h1 [32][72]
  int t = threadIdx.x, w = t >> 6, l = t & 63;
  int qi = blockIdx.x * 4 + w;
  int p = qi >> 9;                             // M1 = 512
  int quad = l >> 4, n16 = l & 15;
  short* wl = lds[w];
  if (l < 32) {
    int nid = nidx[qi * KNB + l];
    const float* pp = pn + ((size_t)p * N + nid) * 3;
    const float* qq = q1 + (size_t)qi * 3;
    float ax = pp[0], ay = pp[1], az = pp[2];
    union { unsigned short s[8]; float4 f; } u;
    u.s[0] = f2bf(ax); u.s[1] = f2bf(ay); u.s[2] = f2bf(az);
    u.s[3] = f2bf(ax - qq[0]); u.s[4] = f2bf(ay - qq[1]); u.s[5] = f2bf(az - qq[2]);
    u.s[6] = 0; u.s[7] = 0;
    float4 z = {0.f, 0.f, 0.f, 0.f};
    float4* d = (float4*)(wl + l * 40);
    d[0] = u.f; d[1] = z; d[2] = z; d[3] = z;
  }
  __syncthreads();
  s8b A1[2];
#pragma unroll
  for (int mf = 0; mf < 2; ++mf)
    A1[mf] = *(const s8b*)(wl + (mf*16 + n16)*40 + quad*8);
  f32x4 zero4 = {0.f, 0.f, 0.f, 0.f};
  {
    f32x4 acc[2][4];
#pragma unroll
    for (int mf = 0; mf < 2; ++mf)
#pragma unroll
      for (int nf = 0; nf < 4; ++nf) acc[mf][nf] = zero4;
    s8b B[4];
#pragma unroll
    for (int nf = 0; nf < 4; ++nf)
      B[nf] = *(const s8b*)(Wa + (nf*16 + n16)*32 + quad*8);
#pragma unroll
    for (int mf = 0; mf < 2; ++mf)
#pragma unroll
      for (int nf = 0; nf < 4; ++nf)
        acc[mf][nf] = mfma16(A1[mf], B[nf], acc[mf][nf]);
#pragma unroll
    for (int nf = 0; nf < 4; ++nf) {
      int col = nf*16 + n16;
      float bias = ba[col];
#pragma unroll
      for (int mf = 0; mf < 2; ++mf)
#pragma unroll
        for (int r = 0; r < 4; ++r) {
          int row = mf*16 + quad*4 + r;
          float h = fmaxf(acc[mf][nf][r] + bias, 0.0f);
          *(unsigned short*)(wl + row*72 + col) = f2bf(h);
        }
    }
  }
  __syncthreads();
  s8b A2[2][2];
#pragma unroll
  for (int mf = 0; mf < 2; ++mf)
#pragma unroll
    for (int kf = 0; kf < 2; ++kf)
      A2[mf][kf] = *(const s8b*)(wl + (mf*16 + n16)*72 + kf*32 + quad*8);
  unsigned vm = vmask[qi];
#pragma unroll
  for (int nc = 0; nc < 2; ++nc) {
    f32x4 acc[2][4];
#pragma unroll
    for (int mf = 0; mf < 2; ++mf)
#pragma unroll
      for (int nf = 0; nf < 4; ++nf) acc[mf][nf] = zero4;
#pragma unroll
    for (int kf = 0; kf < 2; ++kf) {
      s8b B[4];
#pragma unroll
      for (int nf = 0; nf < 4; ++nf)
        B[nf] = *(const s8b*)(Wb + (nc*64 + nf*16 + n16)*64 + kf*32 + quad*8);
#pragma unroll
      for (int mf = 0; mf < 2; ++mf)
#pragma unroll
        for (int nf = 0; nf < 4; ++nf)
          acc[mf][nf] = mfma16(A2[mf][kf], B[nf], acc[mf][nf]);
    }
#pragma unroll
    for (int nf = 0; nf < 4; ++nf) {
      int col = nc*64 + nf*16 + n16;
      float bias = bb[col];
      float m = 0.0f;
#pragma unroll
      for (int mf = 0; mf < 2; ++mf)
#pragma unroll
        for (int r = 0; r < 4; ++r) {
          int row = mf*16 + quad*4 + r;
          float h = fmaxf(acc[mf][nf][r] + bias, 0.0f);
          if ((vm >> row) & 1u) m = fmaxf(m, h);
        }
      m = fmaxf(m, __shfl_xor(m, 16));
      m = fmaxf(m, __shfl_xor(m, 32));
      if (quad == 0) x1b[(size_t)qi * 128 + col] = f2bf(m);
    }
  }
}

// ---------------- layer2 MLP via MFMA: (131->256->384) + masked max ----------------
__global__ __launch_bounds__(256) void k2_mfma(
    const unsigned short* __restrict__ x1b, const float* __restrict__ q1,
    const float* __restrict__ q2, const int* __restrict__ nidx,
    const unsigned* __restrict__ vmask,
    const unsigned short* __restrict__ Wa, const float* __restrict__ ba,
    const unsigned short* __restrict__ Wb, const float* __restrict__ bb,
    float* __restrict__ x2out) {
  __shared__ __align__(16) short lds[4][8448];  // per-wave: feat [32][168] / h1 [32][264]
  int t = threadIdx.x, w = t >> 6, l = t & 63;
  int qi = blockIdx.x * 4 + w;
  int p = qi >> 7;                             // M2 = 128
  int quad = l >> 4, n16 = l & 15;
  short* wl = lds[w];
  {                                            // gather x1 rows (bf16): 2 lanes/row,
    int r = l >> 1, h = l & 1;                 // half-row = 64 bf16 = 8 x float4
    int nid = nidx[qi * KNB + r];
    const float4* s4 = (const float4*)(x1b + (((size_t)p * M1 + nid) << 7) + h * 64);
    float4* d4 = (float4*)(wl + r * 168 + h * 64);
#pragma unroll
    for (int c = 0; c < 8; ++c) d4[c] = s4[c];
  }
  if (l < 32) {                                // rel coords + zero pad k=128..167
    int nid = nidx[qi * KNB + l];
    const float* qn = q1 + ((size_t)p * M1 + nid) * 3;
    const float* qq = q2 + (size_t)qi * 3;
    union { unsigned short s[8]; float4 f; } u;
    u.s[0] = f2bf(qn[0] - qq[0]);
    u.s[1] = f2bf(qn[1] - qq[1]);
    u.s[2] = f2bf(qn[2] - qq[2]);
    u.s[3] = 0; u.s[4] = 0; u.s[5] = 0; u.s[6] = 0; u.s[7] = 0;
    float4 z = {0.f, 0.f, 0.f, 0.f};
    float4* d = (float4*)(wl + l * 168 + 128);
    d[0] = u.f; d[1] = z; d[2] = z; d[3] = z; d[4] = z;
  }
  __syncthreads();
  s8b A1[2][5];
#pragma unroll
  for (int mf = 0; mf < 2; ++mf)
#pragma unroll
    for (int kf = 0; kf < 5; ++kf)
      A1[mf][kf] = *(const s8b*)(wl + (mf*16 + n16)*168 + kf*32 + quad*8);
  f32x4 zero4 = {0.f, 0.f, 0.f, 0.f};
  // GEMM1 -> h1 (ReLU, bf16) back into same per-wave LDS region, stride 264
#pragma unroll
  for (int nc = 0; nc < 4; ++nc) {
    f32x4 acc[2][4];
#pragma unroll
    for (int mf = 0; mf < 2; ++mf)
#pragma unroll
      for (int nf = 0; nf < 4; ++nf) acc[mf][nf] = zero4;
#pragma unroll
    for (int kf = 0; kf < 5; ++kf) {
      s8b B[4];
#pragma unroll
      for (int nf = 0; nf < 4; ++nf)
        B[nf] = *(const s8b*)(Wa + (nc*64 + nf*16 + n16)*160 + kf*32 + quad*8);
#pragma unroll
      for (int mf = 0; mf < 2; ++mf)
#pragma unroll
        for (int nf = 0; nf < 4; ++nf)
          acc[mf][nf] = mfma16(A1[mf][kf], B[nf], acc[mf][nf]);
    }
#pragma unroll
    for (int nf = 0; nf < 4; ++nf) {
      int col = nc*64 + nf*16 + n16;
      float bias = ba[col];
#pragma unroll
      for (int mf = 0; mf < 2; ++mf)
#pragma unroll
        for (int r = 0; r < 4; ++r) {
          int row = mf*16 + quad*4 + r;
          float h = fmaxf(acc[mf][nf][r] + bias, 0.0f);
          *(unsigned short*)(wl + row*264 + col) = f2bf(h);
        }
    }
  }
  __syncthreads();
  s8b A2[2][8];
#pragma unroll
  for (int mf = 0; mf < 2; ++mf)
#pragma unroll
    for (int kf = 0; kf < 8; ++kf)
      A2[mf][kf] = *(const s8b*)(wl + (mf*16 + n16)*264 + kf*32 + quad*8);
  unsigned vm = vmask[qi];
#pragma unroll
  for (int nc = 0; nc < 6; ++nc) {
    f32x4 acc[2][4];
#pragma unroll
    for (int mf = 0; mf < 2; ++mf)
#pragma unroll
      for (int nf = 0; nf < 4; ++nf) acc[mf][nf] = zero4;
#pragma unroll
    for (int kf = 0; kf < 8; ++kf) {
      s8b B[4];
#pragma unroll
      for (int nf = 0; nf < 4; ++nf)
        B[nf] = *(const s8b*)(Wb + (nc*64 + nf*16 + n16)*256 + kf*32 + quad*8);
#pragma unroll
      for (int mf = 0; mf < 2; ++mf)
#pragma unroll
        for (int nf = 0; nf < 4; ++nf)
          acc[mf][nf] = mfma16(A2[mf][kf], B[nf], acc[mf][nf]);
    }
#pragma unroll
    for (int nf = 0; nf < 4; ++nf) {
      int col = nc*64 + nf*16 + n16;
      float bias = bb[col];
      float m = 0.0f;
#pragma unroll
      for (int mf = 0; mf < 2; ++mf)
#pragma unroll
        for (int r = 0; r < 4; ++r) {
          int row = mf*16 + quad*4 + r;
          float h = fmaxf(acc[mf][nf][r] + bias, 0.0f);
          if ((vm >> row) & 1u) m = fmaxf(m, h);
        }
      m = fmaxf(m, __shfl_xor(m, 16));
      m = fmaxf(m, __shfl_xor(m, 32));
      if (quad == 0) x2out[(size_t)qi * 384 + col] = m;
    }
  }
}

// ---------------- layer3 phase 1: (387->512), h1 to ws (fp32) ----------------
__global__ __launch_bounds__(256) void k_mlp3_p1(
    const float* __restrict__ x2, const float* __restrict__ q2,
    const float* __restrict__ W3a, const float* __restrict__ b3a,
    float* __restrict__ h1o) {
  __shared__ __align__(16) float fb[16 * 68];
  __shared__ __align__(16) float wb[16 * 128];
  int t = threadIdx.x;
  int rc = blockIdx.x >> 2, cb = blockIdx.x & 3;
  int rowbase = rc * 64, coutbase = cb * 128;
  int rg = t >> 4, cg = t & 15;
  float acc[4][8];
#pragma unroll
  for (int u = 0; u < 8; ++u) {
    float b = b3a[coutbase + cg*8 + u];
#pragma unroll
    for (int v = 0; v < 4; ++v) acc[v][u] = b;
  }
  for (int jc = 0; jc < 400; jc += 16) {
    __syncthreads();
    for (int i = t; i < 1024; i += 256) {
      int jj = i & 15, r = i >> 4;
      int j = jc + jj, row = rowbase + r;
      float v = 0.0f;
      if (j < 384) v = x2[(size_t)row*384 + j];
      else if (j < 387) v = q2[(size_t)row*3 + (j - 384)];
      fb[jj*68 + r] = v;
    }
    for (int i = t; i < 2048; i += 256) {
      int j = jc + (i >> 7);
      wb[i] = (j < 387) ? W3a[(size_t)j*512 + coutbase + (i & 127)] : 0.0f;
    }
    __syncthreads();
#pragma unroll
    for (int jj = 0; jj < 16; ++jj) {
      float4 rv4 = *(const float4*)&fb[jj*68 + rg*4];
      const float* wp = &wb[jj*128 + cg*8];
      float4 w0 = *(const float4*)&wp[0];
      float4 w1 = *(const float4*)&wp[4];
      float rv[4] = {rv4.x, rv4.y, rv4.z, rv4.w};
      float wv[8] = {w0.x,w0.y,w0.z,w0.w, w1.x,w1.y,w1.z,w1.w};
#pragma unroll
      for (int v = 0; v < 4; ++v)
#pragma unroll
        for (int u = 0; u < 8; ++u) acc[v][u] = fmaf(rv[v], wv[u], acc[v][u]);
    }
  }
#pragma unroll
  for (int v = 0; v < 4; ++v)
#pragma unroll
    for (int u = 0; u < 8; ++u)
      h1o[(size_t)(rowbase + rg*4 + v)*512 + coutbase + cg*8 + u] =
          fmaxf(acc[v][u], 0.0f);
}

// ---------------- layer3 phase 2: (512->768) + global max -> xg ----------------
__global__ __launch_bounds__(256) void k_mlp3_p2(
    const float* __restrict__ h1, const float* __restrict__ W3b,
    const float* __restrict__ b3b, float* __restrict__ xg) {
  __shared__ __align__(16) float fb[16 * 68];
  __shared__ __align__(16) float wb[16 * 192];
  __shared__ int part[192];
  int t = threadIdx.x;
  int rc = blockIdx.x >> 2, cb = blockIdx.x & 3;
  int rowbase = rc * 64, coutbase = cb * 192;
  int p = rc >> 1;
  int rg = t >> 4, cg = t & 15;
  float acc[4][12];
#pragma unroll
  for (int u = 0; u < 12; ++u) {
    float b = b3b[coutbase + cg*12 + u];
#pragma unroll
    for (int v = 0; v < 4; ++v) acc[v][u] = b;
  }
  for (int jc = 0; jc < 512; jc += 16) {
    __syncthreads();
    for (int i = t; i < 1024; i += 256) {
      int jj = i & 15, r = i >> 4;
      fb[jj*68 + r] = h1[(size_t)(rowbase + r)*512 + jc + jj];
    }
#pragma unroll
    for (int jj = 0; jj < 16; ++jj)
      for (int c = t; c < 192; c += 256)
        wb[jj*192 + c] = W3b[(size_t)(jc + jj)*768 + coutbase + c];
    __syncthreads();
#pragma unroll
    for (int jj = 0; jj < 16; ++jj) {
      float4 rv4 = *(const float4*)&fb[jj*68 + rg*4];
      const float* wp = &wb[jj*192 + cg*12];
      float4 w0 = *(const float4*)&wp[0];
      float4 w1 = *(const float4*)&wp[4];
      float4 w2 = *(const float4*)&wp[8];
      float rv[4] = {rv4.x, rv4.y, rv4.z, rv4.w};
      float wv[12] = {w0.x,w0.y,w0.z,w0.w, w1.x,w1.y,w1.z,w1.w, w2.x,w2.y,w2.z,w2.w};
#pragma unroll
      for (int v = 0; v < 4; ++v)
#pragma unroll
        for (int u = 0; u < 12; ++u) acc[v][u] = fmaf(rv[v], wv[u], acc[v][u]);
    }
  }
  for (int i = t; i < 192; i += 256) part[i] = 0;
  __syncthreads();
#pragma unroll
  for (int u = 0; u < 12; ++u) {
    float m = 0.0f;
#pragma unroll
    for (int v = 0; v < 4; ++v) m = fmaxf(m, fmaxf(acc[v][u], 0.0f));
    atomicMax(&part[cg*12 + u], __float_as_int(m));
  }
  __syncthreads();
  if (t < 192)
    atomicMax((int*)&xg[(size_t)p*768 + coutbase + t], part[t]);
}

extern "C" void kernel_launch(void* const* d_in, const int* in_sizes, int n_in,
                              void* d_out, int out_size, void* d_ws, size_t ws_size,
                              hipStream_t stream) {
  const float* pos = (const float*)d_in[0];
  const float* W1a = (const float*)d_in[2];
  const float* b1a = (const float*)d_in[3];
  const float* W1b = (const float*)d_in[4];
  const float* b1b = (const float*)d_in[5];
  const float* W2a = (const float*)d_in[6];
  const float* b2a = (const float*)d_in[7];
  const float* W2b = (const float*)d_in[8];
  const float* b2b = (const float*)d_in[9];
  const float* W3a = (const float*)d_in[10];
  const float* b3a = (const float*)d_in[11];
  const float* W3b = (const float*)d_in[12];
  const float* b3b = (const float*)d_in[13];
  float* out = (float*)d_out;

  // workspace layout (~24.6 MB)
  float* pn   = (float*)d_ws;                       // 393216 f
  float* q1   = pn + (size_t)P * N * 3;             // 98304 f
  float* big  = q1 + (size_t)P * M1 * 3;            // 4194304 f: x1b(bf16) then h13(fp32)
  unsigned short* x1b = (unsigned short*)big;       // 32768*128 shorts
  float* h13  = big;                                // 8192*512 floats (x1b dead by then)
  unsigned short* wp  = (unsigned short*)(big + 4194304);  // 149504 shorts
  unsigned short* Wt1a = wp;
  unsigned short* Wt1b = wp + 2048;
  unsigned short* Wt2a = wp + 10240;
  unsigned short* Wt2b = wp + 51200;
  int* idx1   = (int*)(big + 4194304 + 74752);
  int* idx2   = idx1 + P * M1;
  int* nidx1  = idx2 + P * M2;
  int* nidx2  = nidx1 + (size_t)P * M1 * KNB;
  unsigned* vm1 = (unsigned*)(nidx2 + (size_t)P * M2 * KNB);
  unsigned* vm2 = vm1 + P * M1;

  k_misc<<<225, 256, 0, stream>>>(out);
  k_pack<<<584, 256, 0, stream>>>(W1a, W1b, W2a, W2b, wp);
  k_norm<<<P, 256, 0, stream>>>(pos, pn, out);
  k_fps2<N, M1><<<P, 256, 0, stream>>>(pn, idx1);
  k_gather<<<(P*M1 + 255)/256, 256, 0, stream>>>(pn, idx1, q1, P*M1, M1, N);
  k_neigh<N, M1, N/64><<<P*M1/4, 256, 0, stream>>>(pn, q1, nidx1, vm1, 0.0225f);
  k1_mfma<<<P*M1/4, 256, 0, stream>>>(pn, q1, nidx1, vm1, Wt1a, b1a, Wt1b, b1b, x1b);
  k_fps2<M1, M2><<<P, 256, 0, stream>>>(q1, idx2);
  k_gather<<<(P*M2 + 255)/256, 256, 0, stream>>>(q1, idx2, out + OFF_Q2, P*M2, M2, M1);
  k_neigh<M1, M2, M1/64><<<P*M2/4, 256, 0, stream>>>(q1, out + OFF_Q2, nidx2, vm2, 0.09f);
  k2_mfma<<<P*M2/4, 256, 0, stream>>>(x1b, q1, out + OFF_Q2, nidx2, vm2,
                                      Wt2a, b2a, Wt2b, b2b, out + OFF_X2);
  k_mlp3_p1<<<512, 256, 0, stream>>>(out + OFF_X2, out + OFF_Q2, W3a, b3a, h13);
  k_mlp3_p2<<<512, 256, 0, stream>>>(h13, W3b, b3b, out);
}